// Round 2
// baseline (423.303 us; speedup 1.0000x reference)
//
#include <hip/hip_runtime.h>
#include <hip/hip_bf16.h>
#include <hip/hip_fp16.h>

#define N_NODES 50000
#define E_EDGES 1600000
#define IN_CH 128
#define HID 32
#define HEADS 4
#define HC (HEADS * HID)         // 128
#define OUT_CH 16
#define B_GRAPHS 512
#define NEG_SLOPE 0.2f
#define CAP 96                   // per-node capacity; deg = 1+Pois(32), P(>96)~1e-18
#define NB 512                   // coarse buckets (R15: 2 blocks/CU in k_aggB)
#define BNODES 98                // nodes per bucket (512*98 = 50176 >= 50000)
#define PCAP 3584                // per-bucket edge capacity (mean 3125 + 8.2 sd)
#define ACHUNK 4096              // edges per pass-A block
#define APART 391                // ceil(E_EDGES / ACHUNK)
#define ROWS_PB 64
#define GEMM_BLOCKS 782          // ceil(50000 / 64)
#define TOT_BLOCKS 1173          // APART + GEMM_BLOCKS, interleaved 1:2

__device__ __forceinline__ unsigned short f2bf(float f) {
    unsigned int u = __float_as_uint(f);
    unsigned int r = (u + 0x7FFFu + ((u >> 16) & 1u)) >> 16;   // RNE
    return (unsigned short)r;
}

__device__ __forceinline__ float lrelu_exp(float v) {
    v = v > 0.f ? v : NEG_SLOPE * v;
    return __expf(v);
}

// ---- K1: fused pass-A + GEMM, INTERLEAVED block mapping ------------------
// R16: GEMM part is now LDS-free and barrier-free. W1 (64 KB) is L2-hot
// across all 782 blocks; x rows are read exactly once per block — both
// stream straight from global into the FMA loop (12 independent float4
// loads per kk-group). Attention scores computed in-register via 8-lane
// __shfl_xor head reduction (restash phase + 2 barriers + half-idle tail
// deleted). LDS 48KB -> 16KB (pass-A only); launch_bounds(256,4) pins
// <=128 VGPR -> 16 waves/CU.
__global__ __launch_bounds__(256, 4) void k_fused(const float* __restrict__ x,
                                                  const float* __restrict__ W1,
                                                  const float* __restrict__ att_src,
                                                  const float* __restrict__ att_dst,
                                                  const int* __restrict__ ei,
                                                  unsigned short* __restrict__ hb,
                                                  float* __restrict__ a_s,
                                                  float* __restrict__ a_d,
                                                  int* __restrict__ gcur,
                                                  unsigned int* __restrict__ ebuf,
                                                  float* __restrict__ g) {
    __shared__ float smem[4096];           // 16 KB (pass-A histograms only)
    const int t = threadIdx.x;
    const int bI = blockIdx.x;

    if (bI % 3 == 0) {
        // ---- pass A with per-wave sub-histograms ----
        const int ablk = bI / 3;           // 0..390
        int* scnt = (int*)smem;            // [4][NB] = 8 KB
        int* sbase = scnt + 4 * NB;        // [4][NB] = 8 KB
        const int wv = t >> 6;
        const int e0 = ablk * ACHUNK;
        int e1 = e0 + ACHUNK; if (e1 > E_EDGES) e1 = E_EDGES;
        for (int i = t; i < 4 * NB; i += 256) scnt[i] = 0;
        __syncthreads();
        const int* __restrict__ dstp = ei + E_EDGES;
        for (int e = e0 + t; e < e1; e += 256) {
            int d = dstp[e];
            atomicAdd(&scnt[wv * NB + d / BNODES], 1);
        }
        __syncthreads();
        for (int i = t; i < NB; i += 256) {     // NB > blockDim: loop
            int c0 = scnt[0 * NB + i], c1 = scnt[1 * NB + i];
            int c2 = scnt[2 * NB + i], c3 = scnt[3 * NB + i];
            int base = atomicAdd(&gcur[i], c0 + c1 + c2 + c3);
            sbase[0 * NB + i] = base;
            sbase[1 * NB + i] = base + c0;
            sbase[2 * NB + i] = base + c0 + c1;
            sbase[3 * NB + i] = base + c0 + c1 + c2;
            scnt[0 * NB + i] = 0; scnt[1 * NB + i] = 0;
            scnt[2 * NB + i] = 0; scnt[3 * NB + i] = 0;
        }
        __syncthreads();
        for (int e = e0 + t; e < e1; e += 256) {
            int d = dstp[e];
            int s = ei[e];
            int b = d / BNODES;
            int dl = d - b * BNODES;
            int pos = sbase[wv * NB + b] + atomicAdd(&scnt[wv * NB + b], 1);
            if (pos < PCAP)
                ebuf[(size_t)b * PCAP + pos] = ((unsigned int)dl << 16) | (unsigned int)s;
        }
        return;                            // uniform exit
    }

    // ---- GEMM part: barrier-free, LDS-free, streamed operands ----
    const int bid = bI - bI / 3 - 1;       // 0..781
    const int n0 = bid * ROWS_PB;

    int gt = bid * 256 + t;
    if (gt < B_GRAPHS * HC) g[gt] = 0.f;   // fused g-zero

    const int tx = t & 31;    // col group: cols 4tx..4tx+3
    const int ty = t >> 5;    // row group: rows 8ty..8ty+7

    // row base pointers (clamped; stores are guarded)
    const float* xb[8];
#pragma unroll
    for (int j = 0; j < 8; j++) {
        int n = n0 + ty * 8 + j;
        xb[j] = x + (size_t)(n < N_NODES ? n : 0) * IN_CH;
    }
    const float* wb = W1 + tx * 4;         // col slice base

    float acc[8][4];
#pragma unroll
    for (int j = 0; j < 8; j++)
#pragma unroll
        for (int c = 0; c < 4; c++) acc[j][c] = 0.f;

#pragma unroll 4
    for (int kk = 0; kk < 128; kk += 4) {
        float4 w0 = *(const float4*)(wb + (size_t)(kk + 0) * HC);
        float4 w1 = *(const float4*)(wb + (size_t)(kk + 1) * HC);
        float4 w2 = *(const float4*)(wb + (size_t)(kk + 2) * HC);
        float4 w3 = *(const float4*)(wb + (size_t)(kk + 3) * HC);
#pragma unroll
        for (int j = 0; j < 8; j++) {
            float4 xv = *(const float4*)(xb[j] + kk);
            acc[j][0] += xv.x * w0.x + xv.y * w1.x + xv.z * w2.x + xv.w * w3.x;
            acc[j][1] += xv.x * w0.y + xv.y * w1.y + xv.z * w2.y + xv.w * w3.y;
            acc[j][2] += xv.x * w0.z + xv.y * w1.z + xv.z * w2.z + xv.w * w3.z;
            acc[j][3] += xv.x * w0.w + xv.y * w1.w + xv.z * w2.w + xv.w * w3.w;
        }
    }

#pragma unroll
    for (int j = 0; j < 8; j++) {
        int n = n0 + ty * 8 + j;
        if (n < N_NODES) {
            ushort4 o;
            o.x = f2bf(acc[j][0]); o.y = f2bf(acc[j][1]);
            o.z = f2bf(acc[j][2]); o.w = f2bf(acc[j][3]);
            *(ushort4*)&hb[(size_t)n * HC + tx * 4] = o;
        }
    }

    // attention scores fully in-register: thread (tx,ty) holds
    // h[row][4tx..4tx+3], all 4 cols within head tx>>3. Partial dot +
    // 3-step shfl_xor reduce over the 8-lane head group.
    float4 asv = ((const float4*)att_src)[tx];
    float4 adv = ((const float4*)att_dst)[tx];
    const int head = tx >> 3;
#pragma unroll
    for (int j = 0; j < 8; j++) {
        float sp = acc[j][0] * asv.x + acc[j][1] * asv.y +
                   acc[j][2] * asv.z + acc[j][3] * asv.w;
        float dp = acc[j][0] * adv.x + acc[j][1] * adv.y +
                   acc[j][2] * adv.z + acc[j][3] * adv.w;
        sp += __shfl_xor(sp, 1); sp += __shfl_xor(sp, 2); sp += __shfl_xor(sp, 4);
        dp += __shfl_xor(dp, 1); dp += __shfl_xor(dp, 2); dp += __shfl_xor(dp, 4);
        int n = n0 + ty * 8 + j;
        if ((tx & 7) == 0 && n < N_NODES) {
            a_s[(size_t)n * 4 + head] = sp;
            a_d[(size_t)n * 4 + head] = dp;
        }
    }
}

// ---- K2: fused pass-B + aggregate + pool (one 1024-thr block / bucket) --
// 8-edge unrolled gather: 8 outstanding loads/wave. R15: NB=512 buckets of
// 98 nodes, LDS ~44 KB -> 2 resident blocks/CU = 32 waves.
#define NPW 7                     // ceil(BNODES / 16); waves 14,15 idle
__global__ __launch_bounds__(1024) void k_aggB(const unsigned int* __restrict__ ebuf,
                                               const int* __restrict__ gcur,
                                               const float* __restrict__ a_s,
                                               const float* __restrict__ a_d,
                                               const unsigned short* __restrict__ hb,
                                               const float* __restrict__ b1,
                                               const int* __restrict__ batch,
                                               float* __restrict__ g) {
    __shared__ unsigned short sbuf[BNODES * CAP];   // 18816 B
    __shared__ int scnt[BNODES];                    //   392 B
    __shared__ float sWt[16][4][97];                // 24832 B  (~44 KB total)
    const int t = threadIdx.x;
    const int b = blockIdx.x;
    const int dbase = b * BNODES;

    // phase 1: self-loop seed + LDS scatter of this bucket's edges
    for (int i = t; i < BNODES; i += 1024) {
        int d = dbase + i;
        scnt[i] = (d < N_NODES) ? 1 : 0;
        sbuf[i * CAP] = (unsigned short)d;
    }
    __syncthreads();
    int m = gcur[b]; if (m > PCAP) m = PCAP;
    for (int i = t; i < m; i += 1024) {
        unsigned int p = ebuf[(size_t)b * PCAP + i];
        int dl = p >> 16;
        int s = p & 0xFFFFu;
        int c = atomicAdd(&scnt[dl], 1);
        if (c < CAP) sbuf[dl * CAP + c] = (unsigned short)s;
    }
    __syncthreads();

    // phase 2: wave wv aggregates nodes [wv*NPW, min((wv+1)*NPW, BNODES))
    const int wv = t >> 6;
    const int l = t & 63;
    const int head = l >> 4;
    const int c0 = 2 * l;
    int nl0 = wv * NPW;
    if (nl0 >= BNODES) return;             // waves beyond bucket: uniform exit
    int nl1 = nl0 + NPW; if (nl1 > BNODES) nl1 = BNODES;
    int gn0 = dbase + nl0;
    if (gn0 >= N_NODES) return;
    int gn1 = dbase + nl1; if (gn1 > N_NODES) gn1 = N_NODES;
    const float2 bias = *(const float2*)(b1 + c0);
    float pool0 = 0.f, pool1 = 0.f;
    int cur = batch[gn0];
    for (int n = gn0; n < gn1; n++) {
        int bb = batch[n];
        if (bb != cur) {                   // wave-uniform branch
            atomicAdd(&g[(size_t)cur * HC + c0], pool0);
            atomicAdd(&g[(size_t)cur * HC + c0 + 1], pool1);
            pool0 = pool1 = 0.f;
            cur = bb;
        }
        int nl = n - dbase;
        int c = scnt[nl]; if (c > CAP) c = CAP;
        float4 ad = *(const float4*)(a_d + (size_t)n * 4);
        const unsigned short* __restrict__ srow = &sbuf[nl * CAP];
        for (int i = l; i < c; i += 64) {  // weight fill (this wave only)
            int s = srow[i];
            float4 as = *(const float4*)(a_s + (size_t)s * 4);
            sWt[wv][0][i] = lrelu_exp(as.x + ad.x);
            sWt[wv][1][i] = lrelu_exp(as.y + ad.y);
            sWt[wv][2][i] = lrelu_exp(as.z + ad.z);
            sWt[wv][3][i] = lrelu_exp(as.w + ad.w);
        }
        __asm__ volatile("" ::: "memory"); // wave-coherent LDS
        const float* __restrict__ wrow = &sWt[wv][head][0];
        float acc0 = 0.f, acc1 = 0.f, dsum = 0.f;
        int i = 0;
        for (; i + 8 <= c; i += 8) {       // 8-edge interleave for MLP
            unsigned int u[8];
            float w[8];
#pragma unroll
            for (int q = 0; q < 8; q++) {
                int sq = srow[i + q];
                w[q] = wrow[i + q];
                u[q] = *(const unsigned int*)(hb + (size_t)sq * HC + c0);
            }
#pragma unroll
            for (int q = 0; q < 8; q++) {
                dsum += w[q];
                acc0 += w[q] * __uint_as_float(u[q] << 16);
                acc1 += w[q] * __uint_as_float(u[q] & 0xFFFF0000u);
            }
        }
        for (; i < c; i++) {
            int s0 = srow[i];
            float w0 = wrow[i];
            unsigned int u0 = *(const unsigned int*)(hb + (size_t)s0 * HC + c0);
            dsum += w0;
            acc0 += w0 * __uint_as_float(u0 << 16);
            acc1 += w0 * __uint_as_float(u0 & 0xFFFF0000u);
        }
        __asm__ volatile("" ::: "memory");
        float inv = 1.f / (dsum + 1e-16f);
        float v0 = acc0 * inv + bias.x; v0 = v0 > 0.f ? v0 : (__expf(v0) - 1.f);
        float v1 = acc1 * inv + bias.y; v1 = v1 > 0.f ? v1 : (__expf(v1) - 1.f);
        pool0 += v0;
        pool1 += v1;
    }
    atomicAdd(&g[(size_t)cur * HC + c0], pool0);
    atomicAdd(&g[(size_t)cur * HC + c0 + 1], pool1);
}

// ---------------- K3: tiny 2-layer MLP on pooled graphs ------------------
__global__ __launch_bounds__(64) void k_mlp(const float* __restrict__ g,
                                            const float* __restrict__ w1,
                                            const float* __restrict__ bb1,
                                            const float* __restrict__ w2,
                                            const float* __restrict__ bb2,
                                            float* __restrict__ out) {
    __shared__ float sg[HC];
    __shared__ float st[HID];
    int b = blockIdx.x;
    int t = threadIdx.x;   // 64
    sg[t]      = g[(size_t)b * HC + t];
    sg[t + 64] = g[(size_t)b * HC + 64 + t];
    __syncthreads();
    if (t < HID) {
        float acc = bb1[t];
#pragma unroll 8
        for (int k = 0; k < HC; k++) acc += sg[k] * w1[(size_t)k * HID + t];
        st[t] = acc;
    }
    __syncthreads();
    if (t < OUT_CH) {
        float acc = bb2[t];
#pragma unroll
        for (int k = 0; k < HID; k++) acc += st[k] * w2[(size_t)k * OUT_CH + t];
        out[(size_t)b * OUT_CH + t] = acc;
    }
}

extern "C" void kernel_launch(void* const* d_in, const int* in_sizes, int n_in,
                              void* d_out, int out_size, void* d_ws, size_t ws_size,
                              hipStream_t stream) {
    const float* x       = (const float*)d_in[0];
    const int*   ei      = (const int*)d_in[1];
    const int*   batch   = (const int*)d_in[2];
    const float* W1      = (const float*)d_in[3];
    const float* att_src = (const float*)d_in[4];
    const float* att_dst = (const float*)d_in[5];
    const float* b1      = (const float*)d_in[6];
    const float* lin1_w  = (const float*)d_in[7];
    const float* lin1_b  = (const float*)d_in[8];
    const float* lin2_w  = (const float*)d_in[9];
    const float* lin2_b  = (const float*)d_in[10];
    float* out = (float*)d_out;

    float* ws = (float*)d_ws;
    // layout (float-offsets into ws):
    unsigned short* hb   = (unsigned short*)ws;    // N*128 bf16 -> 3,200,000 floats
    float*  a_s      = ws + 3200000;               //   200,000
    float*  a_d      = ws + 3400000;               //   200,000
    unsigned int* ebuf = (unsigned int*)(ws + 3600000);     // NB*PCAP = 1,835,008
    int*    gcur     = (int*)(ws + 5435008);       //       512 (fits 992-float gap)
    float*  g        = ws + 5436000;               //    65,536
    // total ~5.5M floats = 22 MB

    hipMemsetAsync(gcur, 0, NB * sizeof(int), stream);

    k_fused<<<TOT_BLOCKS, 256, 0, stream>>>(
        x, W1, att_src, att_dst, ei, hb, a_s, a_d, gcur, ebuf, g);
    k_aggB<<<NB, 1024, 0, stream>>>(ebuf, gcur, a_s, a_d, hb, b1, batch, g);
    k_mlp<<<B_GRAPHS, 64, 0, stream>>>(g, lin1_w, lin1_b, lin2_w, lin2_b, out);
}

// Round 3
// 195.633 us; speedup vs baseline: 2.1638x; 2.1638x over previous
//
#include <hip/hip_runtime.h>
#include <hip/hip_bf16.h>
#include <hip/hip_fp16.h>

#define N_NODES 50000
#define E_EDGES 1600000
#define IN_CH 128
#define HID 32
#define HEADS 4
#define HC (HEADS * HID)         // 128
#define OUT_CH 16
#define B_GRAPHS 512
#define NEG_SLOPE 0.2f
#define CAP 96                   // per-node capacity; deg = 1+Pois(32), P(>96)~1e-18
#define NB 512                   // coarse buckets (R15: 2 blocks/CU in k_aggB)
#define BNODES 98                // nodes per bucket (512*98 = 50176 >= 50000)
#define PCAP 3584                // per-bucket edge capacity (mean 3125 + 8.2 sd)
#define ACHUNK 4096              // edges per pass-A block
#define APART 391                // ceil(E_EDGES / ACHUNK)
#define ROWS_PB 64
#define GEMM_BLOCKS 782          // ceil(50000 / 64)
#define TOT_BLOCKS 1173          // APART + GEMM_BLOCKS, interleaved 1:2

__device__ __forceinline__ unsigned short f2bf(float f) {
    unsigned int u = __float_as_uint(f);
    unsigned int r = (u + 0x7FFFu + ((u >> 16) & 1u)) >> 16;   // RNE
    return (unsigned short)r;
}

__device__ __forceinline__ float lrelu_exp(float v) {
    v = v > 0.f ? v : NEG_SLOPE * v;
    return __expf(v);
}

// ---- K1: fused pass-A + GEMM, INTERLEAVED block mapping ------------------
// R17: GEMM body is R12-exact LDS form (120 VGPR — DO NOT stream operands
// from global: R16 tried, compiler clamped to 64 VGPR and spilled, WRITE
// 27->456 MB, 4x slower). Two safe deltas vs R12:
//   (a) attention epilogue in-register via 8-lane shfl_xor (validated in
//       R16's passing run) — restash + 2 barriers + t<128 tail deleted;
//   (b) sW halved to [16][128]: LDS 48->40 KB -> 4 blocks/CU (16 waves,
//       matches 120-VGPR cap of 4 waves/SIMD).
__global__ __launch_bounds__(256) void k_fused(const float* __restrict__ x,
                                               const float* __restrict__ W1,
                                               const float* __restrict__ att_src,
                                               const float* __restrict__ att_dst,
                                               const int* __restrict__ ei,
                                               unsigned short* __restrict__ hb,
                                               float* __restrict__ a_s,
                                               float* __restrict__ a_d,
                                               int* __restrict__ gcur,
                                               unsigned int* __restrict__ ebuf,
                                               float* __restrict__ g) {
    __shared__ float smem[10240];          // 40 KB
    const int t = threadIdx.x;
    const int bI = blockIdx.x;

    if (bI % 3 == 0) {
        // ---- pass A with per-wave sub-histograms (uses 16 KB of smem) ----
        const int ablk = bI / 3;           // 0..390
        int* scnt = (int*)smem;            // [4][NB] = 8 KB
        int* sbase = scnt + 4 * NB;        // [4][NB] = 8 KB
        const int wv = t >> 6;
        const int e0 = ablk * ACHUNK;
        int e1 = e0 + ACHUNK; if (e1 > E_EDGES) e1 = E_EDGES;
        for (int i = t; i < 4 * NB; i += 256) scnt[i] = 0;
        __syncthreads();
        const int* __restrict__ dstp = ei + E_EDGES;
        for (int e = e0 + t; e < e1; e += 256) {
            int d = dstp[e];
            atomicAdd(&scnt[wv * NB + d / BNODES], 1);
        }
        __syncthreads();
        for (int i = t; i < NB; i += 256) {     // NB > blockDim: loop
            int c0 = scnt[0 * NB + i], c1 = scnt[1 * NB + i];
            int c2 = scnt[2 * NB + i], c3 = scnt[3 * NB + i];
            int base = atomicAdd(&gcur[i], c0 + c1 + c2 + c3);
            sbase[0 * NB + i] = base;
            sbase[1 * NB + i] = base + c0;
            sbase[2 * NB + i] = base + c0 + c1;
            sbase[3 * NB + i] = base + c0 + c1 + c2;
            scnt[0 * NB + i] = 0; scnt[1 * NB + i] = 0;
            scnt[2 * NB + i] = 0; scnt[3 * NB + i] = 0;
        }
        __syncthreads();
        for (int e = e0 + t; e < e1; e += 256) {
            int d = dstp[e];
            int s = ei[e];
            int b = d / BNODES;
            int dl = d - b * BNODES;
            int pos = sbase[wv * NB + b] + atomicAdd(&scnt[wv * NB + b], 1);
            if (pos < PCAP)
                ebuf[(size_t)b * PCAP + pos] = ((unsigned int)dl << 16) | (unsigned int)s;
        }
        return;                            // uniform exit
    }

    // ---- GEMM part (R12-exact body, 16-row sW chunks) ----
    float* sX = smem;                      // [64][128] = 32 KB
    float* sW = smem + 8192;               // [16][128] =  8 KB
    const int bid = bI - bI / 3 - 1;       // 0..781
    const int n0 = bid * ROWS_PB;

    int gt = bid * 256 + t;
    if (gt < B_GRAPHS * HC) g[gt] = 0.f;   // fused g-zero

    for (int i = t; i < ROWS_PB * 32; i += 256) {
        int r = i >> 5, c4 = i & 31;
        int n = n0 + r;
        float4 v = (n < N_NODES) ? ((const float4*)x)[(size_t)n * 32 + c4]
                                 : make_float4(0.f, 0.f, 0.f, 0.f);
        ((float4*)sX)[i] = v;
    }

    float acc[8][4];
#pragma unroll
    for (int j = 0; j < 8; j++)
#pragma unroll
        for (int c = 0; c < 4; c++) acc[j][c] = 0.f;

    const int tx = t & 31;    // col group: cols 4tx..4tx+3
    const int ty = t >> 5;    // row group: rows 8ty..8ty+7

    for (int kb = 0; kb < 8; kb++) {
        __syncthreads();
        for (int i = t; i < 16 * 32; i += 256) {
            ((float4*)sW)[i] =
                ((const float4*)W1)[(size_t)(kb * 16 + (i >> 5)) * 32 + (i & 31)];
        }
        __syncthreads();
#pragma unroll
        for (int kk = 0; kk < 16; kk += 4) {
            float4 w0 = *(float4*)&sW[(kk + 0) * 128 + tx * 4];
            float4 w1 = *(float4*)&sW[(kk + 1) * 128 + tx * 4];
            float4 w2 = *(float4*)&sW[(kk + 2) * 128 + tx * 4];
            float4 w3 = *(float4*)&sW[(kk + 3) * 128 + tx * 4];
#pragma unroll
            for (int j = 0; j < 8; j++) {
                float4 xv = *(float4*)&sX[(ty * 8 + j) * 128 + kb * 16 + kk];
                acc[j][0] += xv.x * w0.x + xv.y * w1.x + xv.z * w2.x + xv.w * w3.x;
                acc[j][1] += xv.x * w0.y + xv.y * w1.y + xv.z * w2.y + xv.w * w3.y;
                acc[j][2] += xv.x * w0.z + xv.y * w1.z + xv.z * w2.z + xv.w * w3.z;
                acc[j][3] += xv.x * w0.w + xv.y * w1.w + xv.z * w2.w + xv.w * w3.w;
            }
        }
    }

#pragma unroll
    for (int j = 0; j < 8; j++) {
        int n = n0 + ty * 8 + j;
        if (n < N_NODES) {
            ushort4 o;
            o.x = f2bf(acc[j][0]); o.y = f2bf(acc[j][1]);
            o.z = f2bf(acc[j][2]); o.w = f2bf(acc[j][3]);
            *(ushort4*)&hb[(size_t)n * HC + tx * 4] = o;
        }
    }

    // attention scores fully in-register (validated R16): thread (tx,ty)
    // holds h[row][4tx..4tx+3], all within head tx>>3. Partial dot +
    // 3-step shfl_xor reduce over the 8-lane head group.
    float4 asv = ((const float4*)att_src)[tx];
    float4 adv = ((const float4*)att_dst)[tx];
    const int head = tx >> 3;
#pragma unroll
    for (int j = 0; j < 8; j++) {
        float sp = acc[j][0] * asv.x + acc[j][1] * asv.y +
                   acc[j][2] * asv.z + acc[j][3] * asv.w;
        float dp = acc[j][0] * adv.x + acc[j][1] * adv.y +
                   acc[j][2] * adv.z + acc[j][3] * adv.w;
        sp += __shfl_xor(sp, 1); sp += __shfl_xor(sp, 2); sp += __shfl_xor(sp, 4);
        dp += __shfl_xor(dp, 1); dp += __shfl_xor(dp, 2); dp += __shfl_xor(dp, 4);
        int n = n0 + ty * 8 + j;
        if ((tx & 7) == 0 && n < N_NODES) {
            a_s[(size_t)n * 4 + head] = sp;
            a_d[(size_t)n * 4 + head] = dp;
        }
    }
}

// ---- K2: fused pass-B + aggregate + pool (one 1024-thr block / bucket) --
// 8-edge unrolled gather: 8 outstanding loads/wave. R15: NB=512 buckets of
// 98 nodes, LDS ~44 KB -> 2 resident blocks/CU = 32 waves.
#define NPW 7                     // ceil(BNODES / 16); waves 14,15 idle
__global__ __launch_bounds__(1024) void k_aggB(const unsigned int* __restrict__ ebuf,
                                               const int* __restrict__ gcur,
                                               const float* __restrict__ a_s,
                                               const float* __restrict__ a_d,
                                               const unsigned short* __restrict__ hb,
                                               const float* __restrict__ b1,
                                               const int* __restrict__ batch,
                                               float* __restrict__ g) {
    __shared__ unsigned short sbuf[BNODES * CAP];   // 18816 B
    __shared__ int scnt[BNODES];                    //   392 B
    __shared__ float sWt[16][4][97];                // 24832 B  (~44 KB total)
    const int t = threadIdx.x;
    const int b = blockIdx.x;
    const int dbase = b * BNODES;

    // phase 1: self-loop seed + LDS scatter of this bucket's edges
    for (int i = t; i < BNODES; i += 1024) {
        int d = dbase + i;
        scnt[i] = (d < N_NODES) ? 1 : 0;
        sbuf[i * CAP] = (unsigned short)d;
    }
    __syncthreads();
    int m = gcur[b]; if (m > PCAP) m = PCAP;
    for (int i = t; i < m; i += 1024) {
        unsigned int p = ebuf[(size_t)b * PCAP + i];
        int dl = p >> 16;
        int s = p & 0xFFFFu;
        int c = atomicAdd(&scnt[dl], 1);
        if (c < CAP) sbuf[dl * CAP + c] = (unsigned short)s;
    }
    __syncthreads();

    // phase 2: wave wv aggregates nodes [wv*NPW, min((wv+1)*NPW, BNODES))
    const int wv = t >> 6;
    const int l = t & 63;
    const int head = l >> 4;
    const int c0 = 2 * l;
    int nl0 = wv * NPW;
    if (nl0 >= BNODES) return;             // waves beyond bucket: uniform exit
    int nl1 = nl0 + NPW; if (nl1 > BNODES) nl1 = BNODES;
    int gn0 = dbase + nl0;
    if (gn0 >= N_NODES) return;
    int gn1 = dbase + nl1; if (gn1 > N_NODES) gn1 = N_NODES;
    const float2 bias = *(const float2*)(b1 + c0);
    float pool0 = 0.f, pool1 = 0.f;
    int cur = batch[gn0];
    for (int n = gn0; n < gn1; n++) {
        int bb = batch[n];
        if (bb != cur) {                   // wave-uniform branch
            atomicAdd(&g[(size_t)cur * HC + c0], pool0);
            atomicAdd(&g[(size_t)cur * HC + c0 + 1], pool1);
            pool0 = pool1 = 0.f;
            cur = bb;
        }
        int nl = n - dbase;
        int c = scnt[nl]; if (c > CAP) c = CAP;
        float4 ad = *(const float4*)(a_d + (size_t)n * 4);
        const unsigned short* __restrict__ srow = &sbuf[nl * CAP];
        for (int i = l; i < c; i += 64) {  // weight fill (this wave only)
            int s = srow[i];
            float4 as = *(const float4*)(a_s + (size_t)s * 4);
            sWt[wv][0][i] = lrelu_exp(as.x + ad.x);
            sWt[wv][1][i] = lrelu_exp(as.y + ad.y);
            sWt[wv][2][i] = lrelu_exp(as.z + ad.z);
            sWt[wv][3][i] = lrelu_exp(as.w + ad.w);
        }
        __asm__ volatile("" ::: "memory"); // wave-coherent LDS
        const float* __restrict__ wrow = &sWt[wv][head][0];
        float acc0 = 0.f, acc1 = 0.f, dsum = 0.f;
        int i = 0;
        for (; i + 8 <= c; i += 8) {       // 8-edge interleave for MLP
            unsigned int u[8];
            float w[8];
#pragma unroll
            for (int q = 0; q < 8; q++) {
                int sq = srow[i + q];
                w[q] = wrow[i + q];
                u[q] = *(const unsigned int*)(hb + (size_t)sq * HC + c0);
            }
#pragma unroll
            for (int q = 0; q < 8; q++) {
                dsum += w[q];
                acc0 += w[q] * __uint_as_float(u[q] << 16);
                acc1 += w[q] * __uint_as_float(u[q] & 0xFFFF0000u);
            }
        }
        for (; i < c; i++) {
            int s0 = srow[i];
            float w0 = wrow[i];
            unsigned int u0 = *(const unsigned int*)(hb + (size_t)s0 * HC + c0);
            dsum += w0;
            acc0 += w0 * __uint_as_float(u0 << 16);
            acc1 += w0 * __uint_as_float(u0 & 0xFFFF0000u);
        }
        __asm__ volatile("" ::: "memory");
        float inv = 1.f / (dsum + 1e-16f);
        float v0 = acc0 * inv + bias.x; v0 = v0 > 0.f ? v0 : (__expf(v0) - 1.f);
        float v1 = acc1 * inv + bias.y; v1 = v1 > 0.f ? v1 : (__expf(v1) - 1.f);
        pool0 += v0;
        pool1 += v1;
    }
    atomicAdd(&g[(size_t)cur * HC + c0], pool0);
    atomicAdd(&g[(size_t)cur * HC + c0 + 1], pool1);
}

// ---------------- K3: tiny 2-layer MLP on pooled graphs ------------------
__global__ __launch_bounds__(64) void k_mlp(const float* __restrict__ g,
                                            const float* __restrict__ w1,
                                            const float* __restrict__ bb1,
                                            const float* __restrict__ w2,
                                            const float* __restrict__ bb2,
                                            float* __restrict__ out) {
    __shared__ float sg[HC];
    __shared__ float st[HID];
    int b = blockIdx.x;
    int t = threadIdx.x;   // 64
    sg[t]      = g[(size_t)b * HC + t];
    sg[t + 64] = g[(size_t)b * HC + 64 + t];
    __syncthreads();
    if (t < HID) {
        float acc = bb1[t];
#pragma unroll 8
        for (int k = 0; k < HC; k++) acc += sg[k] * w1[(size_t)k * HID + t];
        st[t] = acc;
    }
    __syncthreads();
    if (t < OUT_CH) {
        float acc = bb2[t];
#pragma unroll
        for (int k = 0; k < HID; k++) acc += st[k] * w2[(size_t)k * OUT_CH + t];
        out[(size_t)b * OUT_CH + t] = acc;
    }
}

extern "C" void kernel_launch(void* const* d_in, const int* in_sizes, int n_in,
                              void* d_out, int out_size, void* d_ws, size_t ws_size,
                              hipStream_t stream) {
    const float* x       = (const float*)d_in[0];
    const int*   ei      = (const int*)d_in[1];
    const int*   batch   = (const int*)d_in[2];
    const float* W1      = (const float*)d_in[3];
    const float* att_src = (const float*)d_in[4];
    const float* att_dst = (const float*)d_in[5];
    const float* b1      = (const float*)d_in[6];
    const float* lin1_w  = (const float*)d_in[7];
    const float* lin1_b  = (const float*)d_in[8];
    const float* lin2_w  = (const float*)d_in[9];
    const float* lin2_b  = (const float*)d_in[10];
    float* out = (float*)d_out;

    float* ws = (float*)d_ws;
    // layout (float-offsets into ws):
    unsigned short* hb   = (unsigned short*)ws;    // N*128 bf16 -> 3,200,000 floats
    float*  a_s      = ws + 3200000;               //   200,000
    float*  a_d      = ws + 3400000;               //   200,000
    unsigned int* ebuf = (unsigned int*)(ws + 3600000);     // NB*PCAP = 1,835,008
    int*    gcur     = (int*)(ws + 5435008);       //       512 (fits 992-float gap)
    float*  g        = ws + 5436000;               //    65,536
    // total ~5.5M floats = 22 MB

    hipMemsetAsync(gcur, 0, NB * sizeof(int), stream);

    k_fused<<<TOT_BLOCKS, 256, 0, stream>>>(
        x, W1, att_src, att_dst, ei, hb, a_s, a_d, gcur, ebuf, g);
    k_aggB<<<NB, 1024, 0, stream>>>(ebuf, gcur, a_s, a_d, hb, b1, batch, g);
    k_mlp<<<B_GRAPHS, 64, 0, stream>>>(g, lin1_w, lin1_b, lin2_w, lin2_b, out);
}